// Round 9
// baseline (268.538 us; speedup 1.0000x reference)
//
#include <hip/hip_runtime.h>

#define NB 2      // batch
#define PP 25     // patch area (5x5)
#define NLVL 6

struct Params {
  const float* x1[NLVL];
  const float* x2[NLVL];
  const float* h[NLVL];
  const float* c[NLVL];
  const float* W[NLVL];
  const float* bias[NLVL];
  float* Dpart[NLVL];   // per-chunk partials, nch * B*S*S*9
  float* D[NLVL];       // lrelu(sum of partials), B*S*S*9
  float* pooled[NLVL];  // pooled corr, B*25*S*S
  float* WT[NLVL];      // repacked weights [(ic*9+t)*100 + oc]
  float* hout[NLVL];
  float* cout[NLVL];
};

__device__ __forceinline__ float lrelu(float v) { return v > 0.f ? v : 0.01f * v; }

// ---------------------------------------------------------------------------
// Repack W[oc][ic][ky][kx] -> WT[(ic*9+t)][oc] so a wave's weight load is
// consecutive floats (lane = oc).
// ---------------------------------------------------------------------------
__global__ __launch_bounds__(256) void repack_kernel(Params pr) {
  const int lvl = blockIdx.y;
  const float* W = pr.W[lvl];
  float* WT = pr.WT[lvl];
  for (int i = blockIdx.x * 256 + threadIdx.x; i < 100 * 450; i += gridDim.x * 256) {
    const int oc = i / 450;
    const int r = i - oc * 450;   // r = ic*9 + (ky*3+kx)
    WT[r * 100 + oc] = W[i];
  }
}

// ---------------------------------------------------------------------------
// dcorr.
// Levels 0-1 (tile path): block = (b, y-tile, channel-chunk); 256 threads =
// 256 distinct sites (xq float4-groups x rows). Channel split is grid-only:
// each thread serially accumulates its chunk's 8 channels (10 indep loads +
// 36 FMAs each, deep ILP, f2 rows 3x-reused via L1) and writes 36 partials
// as 9 coalesced float4 stores. NO LDS, NO syncthreads, NO reduction.
// Levels 2-5: previous LDS-reduction paths (small data, cheap).
// ---------------------------------------------------------------------------
__global__ __launch_bounds__(256) void dcorr_kernel(Params pr) {
  static const int SZt[6] = {64, 32, 16, 8, 4, 2};
  static const int CHt[6] = {512, 1024, 512, 256, 256, 256};
  static const int NCH[6] = {64, 128, 4, 1, 1, 1};
  const int lvl = blockIdx.y;
  const int S = SZt[lvl], C = CHt[lvl], nch = NCH[lvl];
  const int bid = blockIdx.x;
  const int tid = threadIdx.x;
  const size_t nlev = (size_t)NB * S * S * 9;

  if (lvl <= 1) {
    // ---- tile path ----
    int b, y, chunk, xq;
    if (lvl == 0) {
      // bid = ((b*4 + yt)*64 + chunk), 512 blocks
      chunk = bid & 63;
      const int rest = bid >> 6;
      const int yt = rest & 3;
      b = rest >> 2;
      xq = tid & 15;                 // 16 float4 groups cover x=0..63
      y = yt * 16 + (tid >> 4);      // 16 rows per tile
    } else {
      // bid = b*128 + chunk, 256 blocks
      if (bid >= 256) return;
      chunk = bid & 127;
      b = bid >> 7;
      xq = tid & 7;                  // 8 float4 groups cover x=0..31
      y = tid >> 3;                  // all 32 rows
    }
    const int xb0 = xq << 2;
    const int c0 = chunk * 8;        // chpc = 8 both levels

    const float* f1b = pr.x1[lvl] + (((size_t)b * C + c0) * S + y) * S + xb0;
    const float* f2b = pr.x2[lvl] + ((size_t)b * C + c0) * S * S;

    float acc[9][4];
#pragma unroll
    for (int jj = 0; jj < 9; ++jj)
#pragma unroll
      for (int j = 0; j < 4; ++j) acc[jj][j] = 0.f;

#pragma unroll
    for (int t = 0; t < 8; ++t) {
      const float4 f1 = *(const float4*)(f1b + (size_t)t * S * S);
      const float f1a[4] = {f1.x, f1.y, f1.z, f1.w};
      const float* p2 = f2b + (size_t)t * S * S;
#pragma unroll
      for (int dy = 0; dy < 3; ++dy) {
        const int yy = y + dy - 1;
        const bool yok = (yy >= 0) && (yy < S);
        const float* prow = p2 + (size_t)yy * S;
        float4 m;
        float lm, rm;
        if (yok) {
          m = *(const float4*)(prow + xb0);
          lm = (xb0 > 0) ? prow[xb0 - 1] : 0.f;
          rm = (xb0 + 4 < S) ? prow[xb0 + 4] : 0.f;
        } else {
          m = make_float4(0.f, 0.f, 0.f, 0.f);
          lm = 0.f;
          rm = 0.f;
        }
        const float wl[4] = {lm, m.x, m.y, m.z};
        const float wc[4] = {m.x, m.y, m.z, m.w};
        const float wr[4] = {m.y, m.z, m.w, rm};
#pragma unroll
        for (int j = 0; j < 4; ++j) {
          acc[dy * 3 + 0][j] = fmaf(f1a[j], wl[j], acc[dy * 3 + 0][j]);
          acc[dy * 3 + 1][j] = fmaf(f1a[j], wc[j], acc[dy * 3 + 1][j]);
          acc[dy * 3 + 2][j] = fmaf(f1a[j], wr[j], acc[dy * 3 + 2][j]);
        }
      }
    }

    // pack [x][j] (j fastest) and store 9 float4s (144B per thread, runs of
    // consecutive lanes are contiguous)
    float4 buf4[9];
    float* buf = (float*)buf4;
#pragma unroll
    for (int j = 0; j < 4; ++j)
#pragma unroll
      for (int jj = 0; jj < 9; ++jj) buf[j * 9 + jj] = acc[jj][j];
    float* out = pr.Dpart[lvl] + (size_t)chunk * nlev +
                 ((size_t)(b * S + y) * S + xb0) * 9;
#pragma unroll
    for (int v = 0; v < 9; ++v) ((float4*)out)[v] = buf4[v];
    return;
  }

  // ---- levels 2-5: previous reduction paths ----
  const int rows = NB * S;
  if (bid >= rows * nch) return;
  const int row = bid / nch;
  const int chunk = bid - row * nch;
  const int b = row / S, yb = row - b * S;
  float* part = pr.Dpart[lvl] + (size_t)chunk * nlev;

  __shared__ float red[9216];

  if (S >= 16) {
    const int lgq = 2;                 // lvl2: S=16
    const int xqn = S >> 2;
    const int cgn = 256 >> lgq;
    const int xq = tid & (xqn - 1);
    const int cg = tid >> lgq;
    const int chpc = C / nch;
    const int cpt = chpc / cgn;
    const int xb0 = xq << 2;

    const float* f1b = pr.x1[lvl] + (size_t)b * C * S * S + (size_t)yb * S + xb0;
    const float* f2b = pr.x2[lvl] + (size_t)b * C * S * S;

    float acc[9][4];
#pragma unroll
    for (int jj = 0; jj < 9; ++jj)
#pragma unroll
      for (int j = 0; j < 4; ++j) acc[jj][j] = 0.f;

    const int c0 = chunk * chpc + cg;
    for (int t = 0; t < cpt; ++t) {
      const int cc = c0 + t * cgn;
      const float4 f1 = *(const float4*)(f1b + (size_t)cc * S * S);
      const float f1a[4] = {f1.x, f1.y, f1.z, f1.w};
      const float* p2 = f2b + (size_t)cc * S * S;
#pragma unroll
      for (int dy = 0; dy < 3; ++dy) {
        const int yy = yb + dy - 1;
        if (yy < 0 || yy >= S) continue;
        const float* prow = p2 + (size_t)yy * S;
        const float4 m = *(const float4*)(prow + xb0);
        const float lm = (xb0 > 0) ? prow[xb0 - 1] : 0.f;
        const float rm = (xb0 + 4 < S) ? prow[xb0 + 4] : 0.f;
        const float wl[4] = {lm, m.x, m.y, m.z};
        const float wc[4] = {m.x, m.y, m.z, m.w};
        const float wr[4] = {m.y, m.z, m.w, rm};
#pragma unroll
        for (int j = 0; j < 4; ++j) {
          acc[dy * 3 + 0][j] = fmaf(f1a[j], wl[j], acc[dy * 3 + 0][j]);
          acc[dy * 3 + 1][j] = fmaf(f1a[j], wc[j], acc[dy * 3 + 1][j]);
          acc[dy * 3 + 2][j] = fmaf(f1a[j], wr[j], acc[dy * 3 + 2][j]);
        }
      }
    }

    const int n = S * 9;
#pragma unroll
    for (int jj = 0; jj < 9; ++jj)
#pragma unroll
      for (int j = 0; j < 4; ++j)
        red[cg * n + (xb0 + j) * 9 + jj] = acc[jj][j];
    __syncthreads();
    for (int g = cgn >> 1; g >= 1; g >>= 1) {
      for (int i = tid; i < g * n; i += 256) {
        const int c = i / n, e = i - c * n;
        red[c * n + e] += red[(c + g) * n + e];
      }
      __syncthreads();
    }
    float* out = part + (size_t)(b * S + yb) * S * 9;
    for (int i = tid; i < n; i += 256) out[i] = red[i];
  } else {
    const int lg = (S == 8) ? 3 : ((S == 4) ? 2 : 1);
    const int xb = tid & (S - 1), cg = tid >> lg;
    const int NG = 256 >> lg;
    const int cpt = C / NG;

    const float* f1base = pr.x1[lvl] + (size_t)b * C * S * S + (size_t)yb * S + xb;
    const float* f2base = pr.x2[lvl] + (size_t)b * C * S * S;

    float acc[9];
#pragma unroll
    for (int j = 0; j < 9; ++j) acc[j] = 0.f;

    for (int t = 0; t < cpt; ++t) {
      const int cc = cg + t * NG;
      const float f1 = f1base[(size_t)cc * S * S];
      const float* p2 = f2base + (size_t)cc * S * S;
#pragma unroll
      for (int dy = 0; dy < 3; ++dy) {
        const int yy = yb + dy - 1;
        if (yy < 0 || yy >= S) continue;
        const float* prow = p2 + yy * S;
#pragma unroll
        for (int dx = 0; dx < 3; ++dx) {
          const int xx = xb + dx - 1;
          const float v = (xx >= 0 && xx < S) ? prow[xx] : 0.f;
          acc[dy * 3 + dx] += f1 * v;
        }
      }
    }

#pragma unroll
    for (int j = 0; j < 9; ++j) red[tid * 9 + j] = acc[j];
    __syncthreads();
    for (int g = NG >> 1; g >= 1; g >>= 1) {
      if (cg < g) {
#pragma unroll
        for (int j = 0; j < 9; ++j) red[tid * 9 + j] += red[(tid + g * S) * 9 + j];
      }
      __syncthreads();
    }
    if (cg == 0) {
      float* Dp = part + ((size_t)(b * S + yb) * S + xb) * 9;
#pragma unroll
      for (int j = 0; j < 9; ++j) Dp[j] = red[tid * 9 + j];
    }
  }
}

// ---------------------------------------------------------------------------
// dreduce: D = lrelu(sum over chunks of Dpart), float4-vectorized.
// ---------------------------------------------------------------------------
__global__ __launch_bounds__(256) void dreduce_kernel(Params pr) {
  static const int SZt[6] = {64, 32, 16, 8, 4, 2};
  static const int NCH[6] = {64, 128, 4, 1, 1, 1};
  const int lvl = blockIdx.y;
  const int S = SZt[lvl], nch = NCH[lvl];
  const int n4 = (NB * S * S * 9) >> 2;
  const int i4 = blockIdx.x * 256 + threadIdx.x;
  if (i4 >= n4) return;
  const float4* part = (const float4*)pr.Dpart[lvl];
  float4 s = make_float4(0.f, 0.f, 0.f, 0.f);
  for (int c = 0; c < nch; ++c) {
    const float4 v = part[(size_t)c * n4 + i4];
    s.x += v.x; s.y += v.y; s.z += v.z; s.w += v.w;
  }
  float4 o;
  o.x = lrelu(s.x); o.y = lrelu(s.y); o.z = lrelu(s.z); o.w = lrelu(s.w);
  ((float4*)pr.D[lvl])[i4] = o;
}

// ---------------------------------------------------------------------------
// pool: pooled(b,p) = Wk * lreluD(b,p) * Wk^T via separable stencils.
// ---------------------------------------------------------------------------
__global__ __launch_bounds__(256) void pool_kernel(Params pr) {
  static const int SZt[6] = {64, 32, 16, 8, 4, 2};
  static const int NYC[6] = {8, 4, 2, 1, 1, 1};
  static const int LGS[6] = {6, 5, 4, 3, 2, 1};
  const int lvl = blockIdx.y;
  const int S = SZt[lvl], k = lvl + 1, f = 1 << k, nyc = NYC[lvl], lgS = LGS[lvl];
  const int nyo = S / nyc;
  const int bid = blockIdx.x;
  if (bid >= 50 * nyc) return;
  const int yc = bid / 50;
  const int bp = bid - yc * 50;
  const int b = bp / 25, p = bp - (bp / 25) * 25;
  const int dpy = p / 5 - 2, dpx = p - (p / 5) * 5 - 2;
  const int tid = threadIdx.x;
  const int yo0 = yc * nyo;

  __shared__ float ckb[2][130], clb[2][66];
  __shared__ float Dl[5184];
  __shared__ float tmp[1024];

  if (tid == 0) { ckb[0][0] = 1.f; clb[0][0] = 1.f; }
  __syncthreads();
  int rj = 0, cur = 0;
  for (int j = 0; j < k; ++j) {
    const int half = 1 << j, rn = 2 * half - 1;
    float cknew = 0.f, clnew = 0.f;
    if (tid <= 2 * rn) {
      const int t = tid - rn;
#pragma unroll
      for (int e = -1; e <= 1; ++e) {
        const int u = t + e * half;
        if (u >= -rj && u <= rj) cknew += ckb[cur][u + rj];
      }
      cknew *= (1.f / 3.f);
    }
    if (tid < 2 * half) {
      const int y = tid;
      float s = (y < half) ? clb[cur][y] : 0.f;
      const int u = y - half;
      if (u >= -rj && u <= rj) s += ckb[cur][u + rj];
      clnew = s * (1.f / 3.f);
    }
    __syncthreads();
    if (tid <= 2 * rn) ckb[cur ^ 1][tid] = cknew;
    if (tid < 2 * half) clb[cur ^ 1][tid] = clnew;
    __syncthreads();
    cur ^= 1;
    rj = rn;
  }
  const float* ck = ckb[cur];   // index t + (f-1)
  const float* cl = clb[cur];   // index y in [0, f)

  const int yb0 = (yo0 > 0) ? yo0 - 1 : 0;
  const int nyb = (yo0 + nyo - 1) - yb0 + 1;
  const float* Dg = pr.D[lvl] + (size_t)b * S * S * 9 + (size_t)yb0 * S * 9;
  const int nload = nyb * S * 9;
  for (int i = tid; i < nload; i += 256) Dl[i] = Dg[i];
  __syncthreads();

  for (int item = tid; item < nyo * 128; item += 256) {
    const int yol = item >> 7, x = item & 127;
    const int yo = yo0 + yol;
    const int xb = x >> k, tx = x & (f - 1);
    const int txp = tx + dpx;
    const int dxi = (txp < 0) ? 0 : ((txp >= f) ? 2 : 1);
    float sum = 0.f;
    if (yo == 0) {
      for (int y = 0; y < f; ++y) {
        const int typ = y + dpy;
        const int dyi = (typ < 0) ? 0 : ((typ >= f) ? 2 : 1);
        sum += cl[y] * Dl[((0 - yb0) * S + xb) * 9 + dyi * 3 + dxi];
      }
    } else {
      const int ylo = yo * f - (f - 1);
      for (int t = 0; t < 2 * f - 1; ++t) {
        const int y = ylo + t;
        const int yb = y >> k, ty = y & (f - 1);
        const int typ = ty + dpy;
        const int dyi = (typ < 0) ? 0 : ((typ >= f) ? 2 : 1);
        sum += ck[t] * Dl[((yb - yb0) * S + xb) * 9 + dyi * 3 + dxi];
      }
    }
    tmp[yol * 128 + x] = sum;
  }
  __syncthreads();

  float* out = pr.pooled[lvl] + (size_t)(b * PP + p) * S * S;
  for (int item = tid; item < nyo * S; item += 256) {
    const int yol = item >> lgS, xo = item & (S - 1);
    float sum = 0.f;
    if (xo == 0) {
      for (int x = 0; x < f; ++x) sum += cl[x] * tmp[yol * 128 + x];
    } else {
      const int xlo = xo * f - (f - 1);
      for (int t = 0; t < 2 * f - 1; ++t) sum += ck[t] * tmp[yol * 128 + xlo + t];
    }
    out[(size_t)(yo0 + yol) * S + xo] = sum;
  }
}

// ---------------------------------------------------------------------------
// conv (ALL levels) + fused LSTM, ic-split across 4 waves.
// ---------------------------------------------------------------------------
__global__ __launch_bounds__(256) void conv_kernel(Params pr) {
  static const int SZt[6] = {64, 32, 16, 8, 4, 2};
  static const int XTt[6] = {16, 16, 16, 8, 4, 2};   // x-tile per block
  static const int NXGt[6] = {2, 2, 2, 1, 1, 1};     // 8-wide x-groups
  const int lvl = blockIdx.y;
  const int S = SZt[lvl], xtile = XTt[lvl], nxg = NXGt[lvl];
  const int nxt = S / xtile;               // 4,2,1,1,1,1
  const int nblk = NB * S * nxt;
  const int bid = blockIdx.x;
  if (bid >= nblk) return;
  const int b = bid / (S * nxt);
  const int rem = bid - b * (S * nxt);
  const int y = rem / nxt;
  const int xt = rem - y * nxt;
  const int xb0 = xt * xtile;
  const int tid = threadIdx.x;
  const int icc = tid >> 6;                // wave id = ic-chunk id
  const int sub = tid & 63;
  const int nact = 25 * nxg;               // active lanes per wave

  // union buffer: staging 150*20=3000 floats, then partials 4*50*36=7200
  __shared__ float lds[7232];

  // ---- stage input rows [ky][ic][j], j=0 <-> x = xb0-1, width 20
  {
    const float* pooled = pr.pooled[lvl] + (size_t)b * PP * S * S;
    const float* hin = pr.h[lvl] + (size_t)b * PP * S * S;
    for (int i = tid; i < 150 * 20; i += 256) {
      const int r = i / 20, j = i - r * 20;
      const int ky = r / 50, ic = r - ky * 50;
      const int yy = y + ky - 1;
      const int x = xb0 + j - 1;
      float v = 0.f;
      if (yy >= 0 && yy < S && x >= 0 && x < S && j < xtile + 2)
        v = (ic < PP) ? pooled[((size_t)ic * S + yy) * S + x]
                      : hin[((size_t)(ic - PP) * S + yy) * S + x];
      lds[r * 20 + j] = v;
    }
  }
  __syncthreads();

  float acc[4][8];
#pragma unroll
  for (int q = 0; q < 4; ++q)
#pragma unroll
    for (int xx = 0; xx < 8; ++xx) acc[q][xx] = 0.f;

  if (sub < nact) {
    const int xg = sub / 25;
    const int p = sub - xg * 25;
    const int xoff = xg * 8;
    const int ic0 = (icc * 50) >> 2;          // 0,12,25,37
    const int ic1 = ((icc + 1) * 50) >> 2;    // 12,25,37,50
    const float* wbase = pr.WT[lvl] + p;

    float w[4][9], wn[4][9];
#pragma unroll
    for (int q = 0; q < 4; ++q)
#pragma unroll
      for (int t = 0; t < 9; ++t) w[q][t] = wbase[((size_t)ic0 * 9 + t) * 100 + q * 25];

    for (int ic = ic0; ic < ic1; ++ic) {
      const bool pre = (ic + 1 < ic1);
      if (pre) {
        const float* wq = wbase + (size_t)(ic + 1) * 900;
#pragma unroll
        for (int q = 0; q < 4; ++q)
#pragma unroll
          for (int t = 0; t < 9; ++t) wn[q][t] = wq[t * 100 + q * 25];
      }
#pragma unroll
      for (int ky = 0; ky < 3; ++ky) {
        const float4* rp = (const float4*)(lds + (ky * 50 + ic) * 20 + xoff);
        const float4 A = rp[0], Bv = rp[1], Cv = rp[2];
        const float sg[12] = {A.x, A.y, A.z, A.w, Bv.x, Bv.y, Bv.z, Bv.w,
                              Cv.x, Cv.y, Cv.z, Cv.w};
#pragma unroll
        for (int q = 0; q < 4; ++q) {
          const float w0 = w[q][ky * 3], w1 = w[q][ky * 3 + 1], w2 = w[q][ky * 3 + 2];
#pragma unroll
          for (int xx = 0; xx < 8; ++xx)
            acc[q][xx] = fmaf(w0, sg[xx], fmaf(w1, sg[xx + 1], fmaf(w2, sg[xx + 2], acc[q][xx])));
        }
      }
      if (pre) {
#pragma unroll
        for (int q = 0; q < 4; ++q)
#pragma unroll
          for (int t = 0; t < 9; ++t) w[q][t] = wn[q][t];
      }
    }
  }
  __syncthreads();   // staging buffer now dead for all waves

  // ---- write partial gates to LDS (slot stride 36 floats, 16B aligned)
  if (sub < nact) {
    float* slot = lds + (icc * 50 + sub) * 36;
#pragma unroll
    for (int q = 0; q < 4; ++q) {
      ((float4*)slot)[q * 2] = make_float4(acc[q][0], acc[q][1], acc[q][2], acc[q][3]);
      ((float4*)slot)[q * 2 + 1] = make_float4(acc[q][4], acc[q][5], acc[q][6], acc[q][7]);
    }
  }
  __syncthreads();

  // ---- wave 0: reduce over the 4 ic-chunks + fused LSTM
  if (tid < nact) {
    const int xg2 = tid / 25;
    const int p2 = tid - xg2 * 25;
    const int xoff2 = xg2 * 8;

    float g4[4][8];
#pragma unroll
    for (int q = 0; q < 4; ++q)
#pragma unroll
      for (int xx = 0; xx < 8; ++xx) {
        float s = 0.f;
#pragma unroll
        for (int k2 = 0; k2 < 4; ++k2) s += lds[(k2 * 50 + tid) * 36 + q * 8 + xx];
        g4[q][xx] = s;
      }

    const float bi = pr.bias[lvl][p2];
    const float bf = pr.bias[lvl][p2 + 25];
    const float bo = pr.bias[lvl][p2 + 50];
    const float bg = pr.bias[lvl][p2 + 75];
    const size_t base = ((size_t)(b * PP + p2) * S + y) * S + xb0 + xoff2;
    const float* cin = pr.c[lvl] + base;
    float* ho = pr.hout[lvl] + base;
    float* co = pr.cout[lvl] + base;

    float cp[8], hn[8], cn[8];
    if (S >= 8) {
      const float4 c0 = ((const float4*)cin)[0];
      const float4 c1 = ((const float4*)cin)[1];
      cp[0] = c0.x; cp[1] = c0.y; cp[2] = c0.z; cp[3] = c0.w;
      cp[4] = c1.x; cp[5] = c1.y; cp[6] = c1.z; cp[7] = c1.w;
    } else {
#pragma unroll
      for (int xx = 0; xx < 8; ++xx) cp[xx] = (xx < S) ? cin[xx] : 0.f;
    }
#pragma unroll
    for (int xx = 0; xx < 8; ++xx) {
      const float gi = g4[0][xx] + bi;
      const float gf = g4[1][xx] + bf;
      const float go = g4[2][xx] + bo;
      const float gg = g4[3][xx] + bg;
      const float i_ = 1.f / (1.f + __expf(-gi));
      const float f_ = 1.f / (1.f + __expf(-gf));
      const float o_ = 1.f / (1.f + __expf(-go));
      const float g_ = 1.f - 2.f / (__expf(2.f * gg) + 1.f);
      const float c_ = f_ * cp[xx] + i_ * g_;
      const float t2 = 1.f - 2.f / (__expf(2.f * c_) + 1.f);
      cn[xx] = c_;
      hn[xx] = o_ * t2;
    }
    if (S >= 8) {
      ((float4*)ho)[0] = make_float4(hn[0], hn[1], hn[2], hn[3]);
      ((float4*)ho)[1] = make_float4(hn[4], hn[5], hn[6], hn[7]);
      ((float4*)co)[0] = make_float4(cn[0], cn[1], cn[2], cn[3]);
      ((float4*)co)[1] = make_float4(cn[4], cn[5], cn[6], cn[7]);
    } else {
#pragma unroll
      for (int xx = 0; xx < 8; ++xx)
        if (xx < S) { ho[xx] = hn[xx]; co[xx] = cn[xx]; }
    }
  }
}

// ---------------------------------------------------------------------------
extern "C" void kernel_launch(void* const* d_in, const int* in_sizes, int n_in,
                              void* d_out, int out_size, void* d_ws, size_t ws_size,
                              hipStream_t stream) {
  static const int SZ[NLVL] = {64, 32, 16, 8, 4, 2};
  static const int NCH[NLVL] = {64, 128, 4, 1, 1, 1};

  Params pr;
  float* ws = (float*)d_ws;
  size_t off = 0;
  for (int l = 0; l < NLVL; ++l) {
    pr.Dpart[l] = ws + off;
    off += (size_t)NCH[l] * NB * SZ[l] * SZ[l] * 9;
  }
  for (int l = 0; l < NLVL; ++l) { pr.D[l] = ws + off; off += (size_t)NB * SZ[l] * SZ[l] * 9; }
  for (int l = 0; l < NLVL; ++l) { pr.pooled[l] = ws + off; off += (size_t)NB * PP * SZ[l] * SZ[l]; }
  for (int l = 0; l < NLVL; ++l) { pr.WT[l] = ws + off; off += 100 * 450; }

  float* out = (float*)d_out;
  size_t ooff = 0;
  for (int l = 0; l < NLVL; ++l) {
    pr.hout[l] = out + ooff; ooff += (size_t)NB * PP * SZ[l] * SZ[l];
    pr.cout[l] = out + ooff; ooff += (size_t)NB * PP * SZ[l] * SZ[l];
  }

  for (int l = 0; l < NLVL; ++l) {
    pr.x1[l] = (const float*)d_in[4 * l + 0];
    pr.x2[l] = (const float*)d_in[4 * l + 1];
    pr.h[l]  = (const float*)d_in[4 * l + 2];
    pr.c[l]  = (const float*)d_in[4 * l + 3];
    pr.W[l]    = (const float*)d_in[24 + 2 * l];
    pr.bias[l] = (const float*)d_in[25 + 2 * l];
  }

  repack_kernel<<<dim3(45, NLVL), 256, 0, stream>>>(pr);
  dcorr_kernel<<<dim3(512, NLVL), 256, 0, stream>>>(pr);
  dreduce_kernel<<<dim3(72, NLVL), 256, 0, stream>>>(pr);
  pool_kernel<<<dim3(400, NLVL), 256, 0, stream>>>(pr);
  conv_kernel<<<dim3(512, NLVL), 256, 0, stream>>>(pr);
}

// Round 10
// 231.429 us; speedup vs baseline: 1.1603x; 1.1603x over previous
//
#include <hip/hip_runtime.h>

#define NB 2      // batch
#define PP 25     // patch area (5x5)
#define NLVL 6

struct Params {
  const float* x1[NLVL];
  const float* x2[NLVL];
  const float* h[NLVL];
  const float* c[NLVL];
  const float* W[NLVL];
  const float* bias[NLVL];
  float* Dpart[NLVL];   // per-chunk partials, nch * B*S*S*9
  float* D[NLVL];       // lrelu(sum of partials), B*S*S*9
  float* pooled[NLVL];  // pooled corr, B*25*S*S
  float* WT[NLVL];      // repacked weights [(ic*9+t)*100 + oc]
  float* hout[NLVL];
  float* cout[NLVL];
};

__device__ __forceinline__ float lrelu(float v) { return v > 0.f ? v : 0.01f * v; }

// ---------------------------------------------------------------------------
// Repack W[oc][ic][ky][kx] -> WT[(ic*9+t)][oc].
// ---------------------------------------------------------------------------
__global__ __launch_bounds__(256) void repack_kernel(Params pr) {
  const int lvl = blockIdx.y;
  const float* W = pr.W[lvl];
  float* WT = pr.WT[lvl];
  for (int i = blockIdx.x * 256 + threadIdx.x; i < 100 * 450; i += gridDim.x * 256) {
    const int oc = i / 450;
    const int r = i - oc * 450;   // r = ic*9 + (ky*3+kx)
    WT[r * 100 + oc] = W[i];
  }
}

// ---------------------------------------------------------------------------
// dcorr. Levels 0-1: tile path, channel split grid-only (chpc=16), no LDS,
// no reduction. Levels 2-5: LDS-reduction paths.
// ---------------------------------------------------------------------------
__global__ __launch_bounds__(256) void dcorr_kernel(Params pr) {
  static const int SZt[6] = {64, 32, 16, 8, 4, 2};
  static const int CHt[6] = {512, 1024, 512, 256, 256, 256};
  static const int NCH[6] = {32, 64, 4, 1, 1, 1};
  const int lvl = blockIdx.y;
  const int S = SZt[lvl], C = CHt[lvl], nch = NCH[lvl];
  const int bid = blockIdx.x;
  const int tid = threadIdx.x;
  const size_t nlev = (size_t)NB * S * S * 9;

  if (lvl <= 1) {
    // ---- tile path, chpc = 16 ----
    int b, y, chunk, xq;
    if (lvl == 0) {
      // bid = ((b*4 + yt)*32 + chunk), 256 blocks
      chunk = bid & 31;
      const int rest = bid >> 5;
      const int yt = rest & 3;
      b = rest >> 2;
      xq = tid & 15;                 // 16 float4 groups cover x=0..63
      y = yt * 16 + (tid >> 4);      // 16 rows per tile
    } else {
      // bid = b*64 + chunk, 128 blocks
      if (bid >= 128) return;
      chunk = bid & 63;
      b = bid >> 6;
      xq = tid & 7;                  // 8 float4 groups cover x=0..31
      y = tid >> 3;                  // all 32 rows
    }
    const int xb0 = xq << 2;
    const int c0 = chunk * 16;

    const float* f1b = pr.x1[lvl] + (((size_t)b * C + c0) * S + y) * S + xb0;
    const float* f2b = pr.x2[lvl] + ((size_t)b * C + c0) * S * S;

    float acc[9][4];
#pragma unroll
    for (int jj = 0; jj < 9; ++jj)
#pragma unroll
      for (int j = 0; j < 4; ++j) acc[jj][j] = 0.f;

#pragma unroll 4
    for (int t = 0; t < 16; ++t) {
      const float4 f1 = *(const float4*)(f1b + (size_t)t * S * S);
      const float f1a[4] = {f1.x, f1.y, f1.z, f1.w};
      const float* p2 = f2b + (size_t)t * S * S;
#pragma unroll
      for (int dy = 0; dy < 3; ++dy) {
        const int yy = y + dy - 1;
        const bool yok = (yy >= 0) && (yy < S);
        const float* prow = p2 + (size_t)yy * S;
        float4 m;
        float lm, rm;
        if (yok) {
          m = *(const float4*)(prow + xb0);
          lm = (xb0 > 0) ? prow[xb0 - 1] : 0.f;
          rm = (xb0 + 4 < S) ? prow[xb0 + 4] : 0.f;
        } else {
          m = make_float4(0.f, 0.f, 0.f, 0.f);
          lm = 0.f;
          rm = 0.f;
        }
        const float wl[4] = {lm, m.x, m.y, m.z};
        const float wc[4] = {m.x, m.y, m.z, m.w};
        const float wr[4] = {m.y, m.z, m.w, rm};
#pragma unroll
        for (int j = 0; j < 4; ++j) {
          acc[dy * 3 + 0][j] = fmaf(f1a[j], wl[j], acc[dy * 3 + 0][j]);
          acc[dy * 3 + 1][j] = fmaf(f1a[j], wc[j], acc[dy * 3 + 1][j]);
          acc[dy * 3 + 2][j] = fmaf(f1a[j], wr[j], acc[dy * 3 + 2][j]);
        }
      }
    }

    float4 buf4[9];
    float* buf = (float*)buf4;
#pragma unroll
    for (int j = 0; j < 4; ++j)
#pragma unroll
      for (int jj = 0; jj < 9; ++jj) buf[j * 9 + jj] = acc[jj][j];
    float* out = pr.Dpart[lvl] + (size_t)chunk * nlev +
                 ((size_t)(b * S + y) * S + xb0) * 9;
#pragma unroll
    for (int v = 0; v < 9; ++v) ((float4*)out)[v] = buf4[v];
    return;
  }

  // ---- levels 2-5: reduction paths ----
  const int rows = NB * S;
  if (bid >= rows * nch) return;
  const int row = bid / nch;
  const int chunk = bid - row * nch;
  const int b = row / S, yb = row - b * S;
  float* part = pr.Dpart[lvl] + (size_t)chunk * nlev;

  __shared__ float red[9216];

  if (S >= 16) {
    const int lgq = 2;                 // lvl2: S=16
    const int xqn = S >> 2;
    const int cgn = 256 >> lgq;
    const int xq = tid & (xqn - 1);
    const int cg = tid >> lgq;
    const int chpc = C / nch;
    const int cpt = chpc / cgn;
    const int xb0 = xq << 2;

    const float* f1b = pr.x1[lvl] + (size_t)b * C * S * S + (size_t)yb * S + xb0;
    const float* f2b = pr.x2[lvl] + (size_t)b * C * S * S;

    float acc[9][4];
#pragma unroll
    for (int jj = 0; jj < 9; ++jj)
#pragma unroll
      for (int j = 0; j < 4; ++j) acc[jj][j] = 0.f;

    const int c0 = chunk * chpc + cg;
    for (int t = 0; t < cpt; ++t) {
      const int cc = c0 + t * cgn;
      const float4 f1 = *(const float4*)(f1b + (size_t)cc * S * S);
      const float f1a[4] = {f1.x, f1.y, f1.z, f1.w};
      const float* p2 = f2b + (size_t)cc * S * S;
#pragma unroll
      for (int dy = 0; dy < 3; ++dy) {
        const int yy = yb + dy - 1;
        if (yy < 0 || yy >= S) continue;
        const float* prow = p2 + (size_t)yy * S;
        const float4 m = *(const float4*)(prow + xb0);
        const float lm = (xb0 > 0) ? prow[xb0 - 1] : 0.f;
        const float rm = (xb0 + 4 < S) ? prow[xb0 + 4] : 0.f;
        const float wl[4] = {lm, m.x, m.y, m.z};
        const float wc[4] = {m.x, m.y, m.z, m.w};
        const float wr[4] = {m.y, m.z, m.w, rm};
#pragma unroll
        for (int j = 0; j < 4; ++j) {
          acc[dy * 3 + 0][j] = fmaf(f1a[j], wl[j], acc[dy * 3 + 0][j]);
          acc[dy * 3 + 1][j] = fmaf(f1a[j], wc[j], acc[dy * 3 + 1][j]);
          acc[dy * 3 + 2][j] = fmaf(f1a[j], wr[j], acc[dy * 3 + 2][j]);
        }
      }
    }

    const int n = S * 9;
#pragma unroll
    for (int jj = 0; jj < 9; ++jj)
#pragma unroll
      for (int j = 0; j < 4; ++j)
        red[cg * n + (xb0 + j) * 9 + jj] = acc[jj][j];
    __syncthreads();
    for (int g = cgn >> 1; g >= 1; g >>= 1) {
      for (int i = tid; i < g * n; i += 256) {
        const int c = i / n, e = i - c * n;
        red[c * n + e] += red[(c + g) * n + e];
      }
      __syncthreads();
    }
    float* out = part + (size_t)(b * S + yb) * S * 9;
    for (int i = tid; i < n; i += 256) out[i] = red[i];
  } else {
    const int lg = (S == 8) ? 3 : ((S == 4) ? 2 : 1);
    const int xb = tid & (S - 1), cg = tid >> lg;
    const int NG = 256 >> lg;
    const int cpt = C / NG;

    const float* f1base = pr.x1[lvl] + (size_t)b * C * S * S + (size_t)yb * S + xb;
    const float* f2base = pr.x2[lvl] + (size_t)b * C * S * S;

    float acc[9];
#pragma unroll
    for (int j = 0; j < 9; ++j) acc[j] = 0.f;

    for (int t = 0; t < cpt; ++t) {
      const int cc = cg + t * NG;
      const float f1 = f1base[(size_t)cc * S * S];
      const float* p2 = f2base + (size_t)cc * S * S;
#pragma unroll
      for (int dy = 0; dy < 3; ++dy) {
        const int yy = yb + dy - 1;
        if (yy < 0 || yy >= S) continue;
        const float* prow = p2 + yy * S;
#pragma unroll
        for (int dx = 0; dx < 3; ++dx) {
          const int xx = xb + dx - 1;
          const float v = (xx >= 0 && xx < S) ? prow[xx] : 0.f;
          acc[dy * 3 + dx] += f1 * v;
        }
      }
    }

#pragma unroll
    for (int j = 0; j < 9; ++j) red[tid * 9 + j] = acc[j];
    __syncthreads();
    for (int g = NG >> 1; g >= 1; g >>= 1) {
      if (cg < g) {
#pragma unroll
        for (int j = 0; j < 9; ++j) red[tid * 9 + j] += red[(tid + g * S) * 9 + j];
      }
      __syncthreads();
    }
    if (cg == 0) {
      float* Dp = part + ((size_t)(b * S + yb) * S + xb) * 9;
#pragma unroll
      for (int j = 0; j < 9; ++j) Dp[j] = red[tid * 9 + j];
    }
  }
}

// ---------------------------------------------------------------------------
// dreduce: D = lrelu(sum over chunks of Dpart). ILP-8: each batch issues 8
// INDEPENDENT float4 loads then a pairwise tree add, so HBM latency is paid
// once per 8 chunks, not per chunk.
// ---------------------------------------------------------------------------
__global__ __launch_bounds__(256) void dreduce_kernel(Params pr) {
  static const int SZt[6] = {64, 32, 16, 8, 4, 2};
  static const int NCH[6] = {32, 64, 4, 1, 1, 1};
  const int lvl = blockIdx.y;
  const int S = SZt[lvl], nch = NCH[lvl];
  const int n4 = (NB * S * S * 9) >> 2;
  const int i4 = blockIdx.x * 256 + threadIdx.x;
  if (i4 >= n4) return;
  const float4* part = (const float4*)pr.Dpart[lvl];
  float4 s = make_float4(0.f, 0.f, 0.f, 0.f);
  if (nch >= 8) {
    for (int c0 = 0; c0 < nch; c0 += 8) {
      float4 v[8];
#pragma unroll
      for (int k = 0; k < 8; ++k) v[k] = part[(size_t)(c0 + k) * n4 + i4];
#pragma unroll
      for (int k = 0; k < 4; ++k) {
        v[k].x += v[k + 4].x; v[k].y += v[k + 4].y;
        v[k].z += v[k + 4].z; v[k].w += v[k + 4].w;
      }
#pragma unroll
      for (int k = 0; k < 2; ++k) {
        v[k].x += v[k + 2].x; v[k].y += v[k + 2].y;
        v[k].z += v[k + 2].z; v[k].w += v[k + 2].w;
      }
      s.x += v[0].x + v[1].x; s.y += v[0].y + v[1].y;
      s.z += v[0].z + v[1].z; s.w += v[0].w + v[1].w;
    }
  } else {
    for (int c = 0; c < nch; ++c) {
      const float4 v = part[(size_t)c * n4 + i4];
      s.x += v.x; s.y += v.y; s.z += v.z; s.w += v.w;
    }
  }
  float4 o;
  o.x = lrelu(s.x); o.y = lrelu(s.y); o.z = lrelu(s.z); o.w = lrelu(s.w);
  ((float4*)pr.D[lvl])[i4] = o;
}

// ---------------------------------------------------------------------------
// pool: pooled(b,p) = Wk * lreluD(b,p) * Wk^T via separable stencils.
// ---------------------------------------------------------------------------
__global__ __launch_bounds__(256) void pool_kernel(Params pr) {
  static const int SZt[6] = {64, 32, 16, 8, 4, 2};
  static const int NYC[6] = {8, 4, 2, 1, 1, 1};
  static const int LGS[6] = {6, 5, 4, 3, 2, 1};
  const int lvl = blockIdx.y;
  const int S = SZt[lvl], k = lvl + 1, f = 1 << k, nyc = NYC[lvl], lgS = LGS[lvl];
  const int nyo = S / nyc;
  const int bid = blockIdx.x;
  if (bid >= 50 * nyc) return;
  const int yc = bid / 50;
  const int bp = bid - yc * 50;
  const int b = bp / 25, p = bp - (bp / 25) * 25;
  const int dpy = p / 5 - 2, dpx = p - (p / 5) * 5 - 2;
  const int tid = threadIdx.x;
  const int yo0 = yc * nyo;

  __shared__ float ckb[2][130], clb[2][66];
  __shared__ float Dl[5184];
  __shared__ float tmp[1024];

  if (tid == 0) { ckb[0][0] = 1.f; clb[0][0] = 1.f; }
  __syncthreads();
  int rj = 0, cur = 0;
  for (int j = 0; j < k; ++j) {
    const int half = 1 << j, rn = 2 * half - 1;
    float cknew = 0.f, clnew = 0.f;
    if (tid <= 2 * rn) {
      const int t = tid - rn;
#pragma unroll
      for (int e = -1; e <= 1; ++e) {
        const int u = t + e * half;
        if (u >= -rj && u <= rj) cknew += ckb[cur][u + rj];
      }
      cknew *= (1.f / 3.f);
    }
    if (tid < 2 * half) {
      const int y = tid;
      float s = (y < half) ? clb[cur][y] : 0.f;
      const int u = y - half;
      if (u >= -rj && u <= rj) s += ckb[cur][u + rj];
      clnew = s * (1.f / 3.f);
    }
    __syncthreads();
    if (tid <= 2 * rn) ckb[cur ^ 1][tid] = cknew;
    if (tid < 2 * half) clb[cur ^ 1][tid] = clnew;
    __syncthreads();
    cur ^= 1;
    rj = rn;
  }
  const float* ck = ckb[cur];   // index t + (f-1)
  const float* cl = clb[cur];   // index y in [0, f)

  const int yb0 = (yo0 > 0) ? yo0 - 1 : 0;
  const int nyb = (yo0 + nyo - 1) - yb0 + 1;
  const float* Dg = pr.D[lvl] + (size_t)b * S * S * 9 + (size_t)yb0 * S * 9;
  const int nload = nyb * S * 9;
  for (int i = tid; i < nload; i += 256) Dl[i] = Dg[i];
  __syncthreads();

  for (int item = tid; item < nyo * 128; item += 256) {
    const int yol = item >> 7, x = item & 127;
    const int yo = yo0 + yol;
    const int xb = x >> k, tx = x & (f - 1);
    const int txp = tx + dpx;
    const int dxi = (txp < 0) ? 0 : ((txp >= f) ? 2 : 1);
    float sum = 0.f;
    if (yo == 0) {
      for (int y = 0; y < f; ++y) {
        const int typ = y + dpy;
        const int dyi = (typ < 0) ? 0 : ((typ >= f) ? 2 : 1);
        sum += cl[y] * Dl[((0 - yb0) * S + xb) * 9 + dyi * 3 + dxi];
      }
    } else {
      const int ylo = yo * f - (f - 1);
      for (int t = 0; t < 2 * f - 1; ++t) {
        const int y = ylo + t;
        const int yb = y >> k, ty = y & (f - 1);
        const int typ = ty + dpy;
        const int dyi = (typ < 0) ? 0 : ((typ >= f) ? 2 : 1);
        sum += ck[t] * Dl[((yb - yb0) * S + xb) * 9 + dyi * 3 + dxi];
      }
    }
    tmp[yol * 128 + x] = sum;
  }
  __syncthreads();

  float* out = pr.pooled[lvl] + (size_t)(b * PP + p) * S * S;
  for (int item = tid; item < nyo * S; item += 256) {
    const int yol = item >> lgS, xo = item & (S - 1);
    float sum = 0.f;
    if (xo == 0) {
      for (int x = 0; x < f; ++x) sum += cl[x] * tmp[yol * 128 + x];
    } else {
      const int xlo = xo * f - (f - 1);
      for (int t = 0; t < 2 * f - 1; ++t) sum += ck[t] * tmp[yol * 128 + xlo + t];
    }
    out[(size_t)(yo0 + yol) * S + xo] = sum;
  }
}

// ---------------------------------------------------------------------------
// conv (ALL levels) + fused LSTM, ic-split across 4 waves.
// ---------------------------------------------------------------------------
__global__ __launch_bounds__(256) void conv_kernel(Params pr) {
  static const int SZt[6] = {64, 32, 16, 8, 4, 2};
  static const int XTt[6] = {16, 16, 16, 8, 4, 2};   // x-tile per block
  static const int NXGt[6] = {2, 2, 2, 1, 1, 1};     // 8-wide x-groups
  const int lvl = blockIdx.y;
  const int S = SZt[lvl], xtile = XTt[lvl], nxg = NXGt[lvl];
  const int nxt = S / xtile;               // 4,2,1,1,1,1
  const int nblk = NB * S * nxt;
  const int bid = blockIdx.x;
  if (bid >= nblk) return;
  const int b = bid / (S * nxt);
  const int rem = bid - b * (S * nxt);
  const int y = rem / nxt;
  const int xt = rem - y * nxt;
  const int xb0 = xt * xtile;
  const int tid = threadIdx.x;
  const int icc = tid >> 6;                // wave id = ic-chunk id
  const int sub = tid & 63;
  const int nact = 25 * nxg;               // active lanes per wave

  // union buffer: staging 150*20=3000 floats, then partials 4*50*36=7200
  __shared__ float lds[7232];

  // ---- stage input rows [ky][ic][j], j=0 <-> x = xb0-1, width 20
  {
    const float* pooled = pr.pooled[lvl] + (size_t)b * PP * S * S;
    const float* hin = pr.h[lvl] + (size_t)b * PP * S * S;
    for (int i = tid; i < 150 * 20; i += 256) {
      const int r = i / 20, j = i - r * 20;
      const int ky = r / 50, ic = r - ky * 50;
      const int yy = y + ky - 1;
      const int x = xb0 + j - 1;
      float v = 0.f;
      if (yy >= 0 && yy < S && x >= 0 && x < S && j < xtile + 2)
        v = (ic < PP) ? pooled[((size_t)ic * S + yy) * S + x]
                      : hin[((size_t)(ic - PP) * S + yy) * S + x];
      lds[r * 20 + j] = v;
    }
  }
  __syncthreads();

  float acc[4][8];
#pragma unroll
  for (int q = 0; q < 4; ++q)
#pragma unroll
    for (int xx = 0; xx < 8; ++xx) acc[q][xx] = 0.f;

  if (sub < nact) {
    const int xg = sub / 25;
    const int p = sub - xg * 25;
    const int xoff = xg * 8;
    const int ic0 = (icc * 50) >> 2;          // 0,12,25,37
    const int ic1 = ((icc + 1) * 50) >> 2;    // 12,25,37,50
    const float* wbase = pr.WT[lvl] + p;

    float w[4][9], wn[4][9];
#pragma unroll
    for (int q = 0; q < 4; ++q)
#pragma unroll
      for (int t = 0; t < 9; ++t) w[q][t] = wbase[((size_t)ic0 * 9 + t) * 100 + q * 25];

    for (int ic = ic0; ic < ic1; ++ic) {
      const bool pre = (ic + 1 < ic1);
      if (pre) {
        const float* wq = wbase + (size_t)(ic + 1) * 900;
#pragma unroll
        for (int q = 0; q < 4; ++q)
#pragma unroll
          for (int t = 0; t < 9; ++t) wn[q][t] = wq[t * 100 + q * 25];
      }
#pragma unroll
      for (int ky = 0; ky < 3; ++ky) {
        const float4* rp = (const float4*)(lds + (ky * 50 + ic) * 20 + xoff);
        const float4 A = rp[0], Bv = rp[1], Cv = rp[2];
        const float sg[12] = {A.x, A.y, A.z, A.w, Bv.x, Bv.y, Bv.z, Bv.w,
                              Cv.x, Cv.y, Cv.z, Cv.w};
#pragma unroll
        for (int q = 0; q < 4; ++q) {
          const float w0 = w[q][ky * 3], w1 = w[q][ky * 3 + 1], w2 = w[q][ky * 3 + 2];
#pragma unroll
          for (int xx = 0; xx < 8; ++xx)
            acc[q][xx] = fmaf(w0, sg[xx], fmaf(w1, sg[xx + 1], fmaf(w2, sg[xx + 2], acc[q][xx])));
        }
      }
      if (pre) {
#pragma unroll
        for (int q = 0; q < 4; ++q)
#pragma unroll
          for (int t = 0; t < 9; ++t) w[q][t] = wn[q][t];
      }
    }
  }
  __syncthreads();   // staging buffer now dead for all waves

  // ---- write partial gates to LDS (slot stride 36 floats, 16B aligned)
  if (sub < nact) {
    float* slot = lds + (icc * 50 + sub) * 36;
#pragma unroll
    for (int q = 0; q < 4; ++q) {
      ((float4*)slot)[q * 2] = make_float4(acc[q][0], acc[q][1], acc[q][2], acc[q][3]);
      ((float4*)slot)[q * 2 + 1] = make_float4(acc[q][4], acc[q][5], acc[q][6], acc[q][7]);
    }
  }
  __syncthreads();

  // ---- wave 0: reduce over the 4 ic-chunks + fused LSTM
  if (tid < nact) {
    const int xg2 = tid / 25;
    const int p2 = tid - xg2 * 25;
    const int xoff2 = xg2 * 8;

    float g4[4][8];
#pragma unroll
    for (int q = 0; q < 4; ++q)
#pragma unroll
      for (int xx = 0; xx < 8; ++xx) {
        float s = 0.f;
#pragma unroll
        for (int k2 = 0; k2 < 4; ++k2) s += lds[(k2 * 50 + tid) * 36 + q * 8 + xx];
        g4[q][xx] = s;
      }

    const float bi = pr.bias[lvl][p2];
    const float bf = pr.bias[lvl][p2 + 25];
    const float bo = pr.bias[lvl][p2 + 50];
    const float bg = pr.bias[lvl][p2 + 75];
    const size_t base = ((size_t)(b * PP + p2) * S + y) * S + xb0 + xoff2;
    const float* cin = pr.c[lvl] + base;
    float* ho = pr.hout[lvl] + base;
    float* co = pr.cout[lvl] + base;

    float cp[8], hn[8], cn[8];
    if (S >= 8) {
      const float4 c0 = ((const float4*)cin)[0];
      const float4 c1 = ((const float4*)cin)[1];
      cp[0] = c0.x; cp[1] = c0.y; cp[2] = c0.z; cp[3] = c0.w;
      cp[4] = c1.x; cp[5] = c1.y; cp[6] = c1.z; cp[7] = c1.w;
    } else {
#pragma unroll
      for (int xx = 0; xx < 8; ++xx) cp[xx] = (xx < S) ? cin[xx] : 0.f;
    }
#pragma unroll
    for (int xx = 0; xx < 8; ++xx) {
      const float gi = g4[0][xx] + bi;
      const float gf = g4[1][xx] + bf;
      const float go = g4[2][xx] + bo;
      const float gg = g4[3][xx] + bg;
      const float i_ = 1.f / (1.f + __expf(-gi));
      const float f_ = 1.f / (1.f + __expf(-gf));
      const float o_ = 1.f / (1.f + __expf(-go));
      const float g_ = 1.f - 2.f / (__expf(2.f * gg) + 1.f);
      const float c_ = f_ * cp[xx] + i_ * g_;
      const float t2 = 1.f - 2.f / (__expf(2.f * c_) + 1.f);
      cn[xx] = c_;
      hn[xx] = o_ * t2;
    }
    if (S >= 8) {
      ((float4*)ho)[0] = make_float4(hn[0], hn[1], hn[2], hn[3]);
      ((float4*)ho)[1] = make_float4(hn[4], hn[5], hn[6], hn[7]);
      ((float4*)co)[0] = make_float4(cn[0], cn[1], cn[2], cn[3]);
      ((float4*)co)[1] = make_float4(cn[4], cn[5], cn[6], cn[7]);
    } else {
#pragma unroll
      for (int xx = 0; xx < 8; ++xx)
        if (xx < S) { ho[xx] = hn[xx]; co[xx] = cn[xx]; }
    }
  }
}

// ---------------------------------------------------------------------------
extern "C" void kernel_launch(void* const* d_in, const int* in_sizes, int n_in,
                              void* d_out, int out_size, void* d_ws, size_t ws_size,
                              hipStream_t stream) {
  static const int SZ[NLVL] = {64, 32, 16, 8, 4, 2};
  static const int NCH[NLVL] = {32, 64, 4, 1, 1, 1};

  Params pr;
  float* ws = (float*)d_ws;
  size_t off = 0;
  for (int l = 0; l < NLVL; ++l) {
    pr.Dpart[l] = ws + off;
    off += (size_t)NCH[l] * NB * SZ[l] * SZ[l] * 9;
  }
  for (int l = 0; l < NLVL; ++l) { pr.D[l] = ws + off; off += (size_t)NB * SZ[l] * SZ[l] * 9; }
  for (int l = 0; l < NLVL; ++l) { pr.pooled[l] = ws + off; off += (size_t)NB * PP * SZ[l] * SZ[l]; }
  for (int l = 0; l < NLVL; ++l) { pr.WT[l] = ws + off; off += 100 * 450; }

  float* out = (float*)d_out;
  size_t ooff = 0;
  for (int l = 0; l < NLVL; ++l) {
    pr.hout[l] = out + ooff; ooff += (size_t)NB * PP * SZ[l] * SZ[l];
    pr.cout[l] = out + ooff; ooff += (size_t)NB * PP * SZ[l] * SZ[l];
  }

  for (int l = 0; l < NLVL; ++l) {
    pr.x1[l] = (const float*)d_in[4 * l + 0];
    pr.x2[l] = (const float*)d_in[4 * l + 1];
    pr.h[l]  = (const float*)d_in[4 * l + 2];
    pr.c[l]  = (const float*)d_in[4 * l + 3];
    pr.W[l]    = (const float*)d_in[24 + 2 * l];
    pr.bias[l] = (const float*)d_in[25 + 2 * l];
  }

  repack_kernel<<<dim3(45, NLVL), 256, 0, stream>>>(pr);
  dcorr_kernel<<<dim3(256, NLVL), 256, 0, stream>>>(pr);
  dreduce_kernel<<<dim3(72, NLVL), 256, 0, stream>>>(pr);
  pool_kernel<<<dim3(400, NLVL), 256, 0, stream>>>(pr);
  conv_kernel<<<dim3(512, NLVL), 256, 0, stream>>>(pr);
}